// Round 1
// baseline (143.912 us; speedup 1.0000x reference)
//
#include <hip/hip_runtime.h>
#include <hip/hip_bf16.h>

#define C_   512
#define HS   128
#define NN   10368   // 18*24*24

typedef __bf16 bf16x8 __attribute__((ext_vector_type(8)));
typedef float  f32x4  __attribute__((ext_vector_type(4)));

// ---------------------------------------------------------------------------
// K1: cast features fp32 [C][N] -> xb bf16 [C][N] and xbT bf16 [N][C]
// 64x64 tiles via LDS (stride 65 -> conflict-free transpose)
// ---------------------------------------------------------------------------
__global__ void k_cast_transpose(const float* __restrict__ x,
                                 __bf16* __restrict__ xb,
                                 __bf16* __restrict__ xbT) {
    __shared__ float tile[64][65];
    const int bc = blockIdx.x;          // 0..7   (c block of 64)
    const int bn = blockIdx.y;          // 0..161 (n block of 64)
    const int t  = threadIdx.x;         // 0..255
    const int tr = t >> 6;              // 0..3 (wave-uniform)
    const int tn = t & 63;
    const int c0 = bc * 64, n0 = bn * 64;
    for (int i = 0; i < 16; i++) {
        int c = tr + i * 4;
        float v = x[(size_t)(c0 + c) * NN + n0 + tn];
        xb[(size_t)(c0 + c) * NN + n0 + tn] = (__bf16)v;
        tile[c][tn] = v;
    }
    __syncthreads();
    for (int i = 0; i < 16; i++) {
        int n = tr + i * 4;
        xbT[(size_t)(n0 + n) * C_ + c0 + tn] = (__bf16)tile[tn][n];
    }
}

// ---------------------------------------------------------------------------
// K0: cast weights to bf16, zero the fp32 M accumulator (192K threads)
// ---------------------------------------------------------------------------
__global__ void k_prep(const float* __restrict__ Wi, const float* __restrict__ Wj,
                       __bf16* __restrict__ Wib, __bf16* __restrict__ Wjb,
                       float* __restrict__ Mtf) {
    int i = blockIdx.x * 256 + threadIdx.x;
    if (i < 65536)        Wib[i] = (__bf16)Wi[i];
    else if (i < 131072)  Wjb[i - 65536] = (__bf16)Wj[i - 65536];
    else                  Mtf[i - 131072] = 0.f;
}

// ---------------------------------------------------------------------------
// K2 (fused G1+G2): 1296 waves.
//   waves [0,648):   fj[h][n]   = sum_c Wj[h][c]*x[c][n] + bj[h]
//                    A = Wjb [128][512], Bt = xbT [N][512]
//   waves [648,1296) finm[n][h] = sum_c x[c][n]*Wi[h][c] + bi[h]
//                    A = xbT [N][512],  Bt = Wib [128][512]
// ---------------------------------------------------------------------------
__global__ void k_gemm12(const __bf16* __restrict__ xbT,
                         const __bf16* __restrict__ Wib, const __bf16* __restrict__ Wjb,
                         const float* __restrict__ bi, const float* __restrict__ bj,
                         __bf16* __restrict__ fj, __bf16* __restrict__ finm) {
    const int w    = blockIdx.x * 4 + (threadIdx.x >> 6);
    const int lane = threadIdx.x & 63;
    const int l16  = lane & 15;
    const int q    = lane >> 4;
    if (w < 648) {
        const int h0 = (w & 3) * 32, n0 = (w >> 2) * 64;
        f32x4 acc[2][4] = {};
        for (int k = 0; k < 512; k += 32) {
            bf16x8 a[2], b[4];
            #pragma unroll
            for (int i = 0; i < 2; i++)
                a[i] = *(const bf16x8*)(Wjb + (h0 + 16 * i + l16) * 512 + k + q * 8);
            #pragma unroll
            for (int t = 0; t < 4; t++)
                b[t] = *(const bf16x8*)(xbT + (size_t)(n0 + 16 * t + l16) * 512 + k + q * 8);
            #pragma unroll
            for (int i = 0; i < 2; i++)
                #pragma unroll
                for (int t = 0; t < 4; t++)
                    acc[i][t] = __builtin_amdgcn_mfma_f32_16x16x32_bf16(a[i], b[t], acc[i][t], 0, 0, 0);
        }
        #pragma unroll
        for (int i = 0; i < 2; i++)
            #pragma unroll
            for (int t = 0; t < 4; t++)
                #pragma unroll
                for (int r = 0; r < 4; r++) {
                    int h = h0 + 16 * i + q * 4 + r;
                    int n = n0 + 16 * t + l16;
                    fj[(size_t)h * NN + n] = (__bf16)(acc[i][t][r] + bj[h]);
                }
    } else {
        const int w2 = w - 648;
        const int n0 = (w2 >> 2) * 64, h0 = (w2 & 3) * 32;
        f32x4 acc[4][2] = {};
        for (int k = 0; k < 512; k += 32) {
            bf16x8 a[4], b[2];
            #pragma unroll
            for (int i = 0; i < 4; i++)
                a[i] = *(const bf16x8*)(xbT + (size_t)(n0 + 16 * i + l16) * 512 + k + q * 8);
            #pragma unroll
            for (int t = 0; t < 2; t++)
                b[t] = *(const bf16x8*)(Wib + (h0 + 16 * t + l16) * 512 + k + q * 8);
            #pragma unroll
            for (int i = 0; i < 4; i++)
                #pragma unroll
                for (int t = 0; t < 2; t++)
                    acc[i][t] = __builtin_amdgcn_mfma_f32_16x16x32_bf16(a[i], b[t], acc[i][t], 0, 0, 0);
        }
        #pragma unroll
        for (int i = 0; i < 4; i++)
            #pragma unroll
            for (int t = 0; t < 2; t++)
                #pragma unroll
                for (int r = 0; r < 4; r++) {
                    int n = n0 + 16 * i + q * 4 + r;
                    int h = h0 + 16 * t + l16;
                    finm[(size_t)n * HS + h] = (__bf16)(acc[i][t][r] + bi[h]);
                }
    }
}

// ---------------------------------------------------------------------------
// K3 (G3): MT[c][h] = sum_n xb[c][n] * fj[h][n]
//   A = xb [512][NN], Bt = fj [128][NN]; wave tile 32c x 32h; split-K 18,
//   18 k-steps (of 32) each; fp32 atomicAdd into Mtf.
// ---------------------------------------------------------------------------
__global__ void k_gemm3(const __bf16* __restrict__ xb, const __bf16* __restrict__ fj,
                        float* __restrict__ Mtf) {
    const int w    = blockIdx.x * 4 + (threadIdx.x >> 6);   // 0..1151
    const int lane = threadIdx.x & 63;
    const int l16  = lane & 15;
    const int q    = lane >> 4;
    const int tp = w & 63, chunk = w >> 6;                  // 64 tiles x 18 chunks
    const int c0 = (tp >> 2) * 32, h0 = (tp & 3) * 32;
    const int k0 = chunk * 18 * 32;
    f32x4 acc[2][2] = {};
    for (int s = 0; s < 18; s++) {
        int k = k0 + s * 32;
        bf16x8 a[2], b[2];
        #pragma unroll
        for (int i = 0; i < 2; i++)
            a[i] = *(const bf16x8*)(xb + (size_t)(c0 + 16 * i + l16) * NN + k + q * 8);
        #pragma unroll
        for (int t = 0; t < 2; t++)
            b[t] = *(const bf16x8*)(fj + (size_t)(h0 + 16 * t + l16) * NN + k + q * 8);
        #pragma unroll
        for (int i = 0; i < 2; i++)
            #pragma unroll
            for (int t = 0; t < 2; t++)
                acc[i][t] = __builtin_amdgcn_mfma_f32_16x16x32_bf16(a[i], b[t], acc[i][t], 0, 0, 0);
    }
    #pragma unroll
    for (int i = 0; i < 2; i++)
        #pragma unroll
        for (int t = 0; t < 2; t++)
            #pragma unroll
            for (int r = 0; r < 4; r++) {
                int c = c0 + 16 * i + q * 4 + r;
                int h = h0 + 16 * t + l16;
                atomicAdd(&Mtf[c * HS + h], acc[i][t][r]);
            }
}

// ---------------------------------------------------------------------------
// K3b: Mtb = bf16(Mtf * agg/N)   (64K elements)
// ---------------------------------------------------------------------------
__global__ void k_scale(const float* __restrict__ Mtf, const float* __restrict__ agg,
                        __bf16* __restrict__ Mtb) {
    int i = blockIdx.x * 256 + threadIdx.x;
    float scale = agg[0] / (float)NN;
    if (i < 65536) Mtb[i] = (__bf16)(Mtf[i] * scale);
}

// ---------------------------------------------------------------------------
// K4 (G4 + epilogue): out[c][n] = feat[c][n] + sum_h Mtb[c][h]*finm[n][h]
//   A = Mtb [512][128], Bt = finm [NN][128]; wave tile 32c x 64n; K=128.
// ---------------------------------------------------------------------------
__global__ void k_gemm4(const __bf16* __restrict__ Mtb, const __bf16* __restrict__ finm,
                        const float* __restrict__ feat, float* __restrict__ out) {
    const int w    = blockIdx.x * 4 + (threadIdx.x >> 6);   // 0..2591
    const int lane = threadIdx.x & 63;
    const int l16  = lane & 15;
    const int q    = lane >> 4;
    const int c0 = (w & 15) * 32, n0 = (w >> 4) * 64;
    f32x4 acc[2][4] = {};
    for (int k = 0; k < 128; k += 32) {
        bf16x8 a[2], b[4];
        #pragma unroll
        for (int i = 0; i < 2; i++)
            a[i] = *(const bf16x8*)(Mtb + (c0 + 16 * i + l16) * 128 + k + q * 8);
        #pragma unroll
        for (int t = 0; t < 4; t++)
            b[t] = *(const bf16x8*)(finm + (size_t)(n0 + 16 * t + l16) * 128 + k + q * 8);
        #pragma unroll
        for (int i = 0; i < 2; i++)
            #pragma unroll
            for (int t = 0; t < 4; t++)
                acc[i][t] = __builtin_amdgcn_mfma_f32_16x16x32_bf16(a[i], b[t], acc[i][t], 0, 0, 0);
    }
    #pragma unroll
    for (int i = 0; i < 2; i++)
        #pragma unroll
        for (int t = 0; t < 4; t++)
            #pragma unroll
            for (int r = 0; r < 4; r++) {
                int c = c0 + 16 * i + q * 4 + r;
                int n = n0 + 16 * t + l16;
                size_t idx = (size_t)c * NN + n;
                out[idx] = feat[idx] + acc[i][t][r];
            }
}

// ---------------------------------------------------------------------------
// Workspace layout (bytes, all 256-aligned):
//   xb   @ 0          : 512*10368*2  = 10,616,832
//   xbT  @ 10,616,832 : 10,616,832
//   Wib  @ 21,233,664 : 131,072
//   Wjb  @ 21,364,736 : 131,072
//   fj   @ 21,495,808 : 2,654,208
//   finm @ 24,150,016 : 2,654,208
//   Mtf  @ 26,804,224 : 262,144
//   Mtb  @ 27,066,368 : 131,072     total = 27,197,440 B (~27.2 MB)
// ---------------------------------------------------------------------------
extern "C" void kernel_launch(void* const* d_in, const int* in_sizes, int n_in,
                              void* d_out, int out_size, void* d_ws, size_t ws_size,
                              hipStream_t stream) {
    const float* feat = (const float*)d_in[0];
    const float* Wi   = (const float*)d_in[1];
    const float* bi   = (const float*)d_in[2];
    const float* Wj   = (const float*)d_in[3];
    const float* bj   = (const float*)d_in[4];
    const float* agg  = (const float*)d_in[5];
    float* out = (float*)d_out;

    char* ws = (char*)d_ws;
    __bf16* xb   = (__bf16*)(ws);
    __bf16* xbT  = (__bf16*)(ws + 10616832);
    __bf16* Wib  = (__bf16*)(ws + 21233664);
    __bf16* Wjb  = (__bf16*)(ws + 21364736);
    __bf16* fj   = (__bf16*)(ws + 21495808);
    __bf16* finm = (__bf16*)(ws + 24150016);
    float*  Mtf  = (float*) (ws + 26804224);
    __bf16* Mtb  = (__bf16*)(ws + 27066368);

    k_cast_transpose<<<dim3(8, 162), 256, 0, stream>>>(feat, xb, xbT);
    k_prep<<<768, 256, 0, stream>>>(Wi, Wj, Wib, Wjb, Mtf);
    k_gemm12<<<324, 256, 0, stream>>>(xbT, Wib, Wjb, bi, bj, fj, finm);
    k_gemm3<<<288, 256, 0, stream>>>(xb, fj, Mtf);
    k_scale<<<256, 256, 0, stream>>>(Mtf, agg, Mtb);
    k_gemm4<<<648, 256, 0, stream>>>(Mtb, finm, feat, out);
}